// Round 2
// baseline (286.171 us; speedup 1.0000x reference)
//
#include <hip/hip_runtime.h>

// PythonRenderer: per-pixel barycentric interpolation renderer.
// Inputs (setup_inputs order):
//   0: v2d      [B,V,3]  float32
//   1: vt       [T,2]    float32
//   2: vi       [F,3]    int32
//   3: vti      [F,3]    int32
//   4: index_img[B,H,W]  int32
//   5: vn       [B,V,3]  float32
// Outputs concatenated flat in d_out (float32):
//   depth [B,H,W]      offset 0
//   bary  [B,H,W,3]    offset NPIX
//   vt    [B,H,W,2]    offset NPIX*4
//   vn    [B,H,W,3]    offset NPIX*6
//
// NOTE on numerics: the reference has epsclamp(det) with EPS=1e-8 —
// near-degenerate triangles amplify last-ulp differences by ~1e16, so we
// must match numpy's exact op order and must NOT let the compiler contract
// mul+add into FMA (sign of det decides everything). Hence
// `#pragma clang fp contract(off)` and explicit left-to-right association.

#define EPSV 1e-8f

__device__ __forceinline__ float epsclamp(float x) {
    return x < 0.0f ? fminf(x, -EPSV) : fmaxf(x, EPSV);
}

__global__ __launch_bounds__(256) void render_px(
    const float* __restrict__ v2d,
    const float* __restrict__ vt,
    const int*   __restrict__ vi,
    const int*   __restrict__ vti,
    const int*   __restrict__ index_img,
    const float* __restrict__ vn,
    float* __restrict__ out)
{
#pragma clang fp contract(off)
    constexpr int W = 1024, H = 1024, V = 98304;
    constexpr int NPIX = 4 * 1024 * 1024;

    const int p = blockIdx.x * 256 + threadIdx.x;
    if (p >= NPIX) return;

    const int x = p & (W - 1);
    const int y = (p >> 10) & (H - 1);
    const int b = p >> 20;

    const int idx = index_img[p];
    const float fm = (idx != -1) ? 1.0f : 0.0f;
    const int f = (idx < 0) ? 0 : idx;

    // face -> vertex / uv indices (random gathers into 2.25MB tables)
    const int i0 = vi[3 * f + 0];
    const int i1 = vi[3 * f + 1];
    const int i2 = vi[3 * f + 2];
    const int t0i = vti[3 * f + 0];
    const int t1i = vti[3 * f + 1];
    const int t2i = vti[3 * f + 2];

    // screen-space vertices (per-batch table)
    const float* __restrict__ vb = v2d + (size_t)b * V * 3;
    const float p0x = vb[3 * i0 + 0], p0y = vb[3 * i0 + 1], p0z = vb[3 * i0 + 2];
    const float p1x = vb[3 * i1 + 0], p1y = vb[3 * i1 + 1], p1z = vb[3 * i1 + 2];
    const float p2x = vb[3 * i2 + 0], p2y = vb[3 * i2 + 1], p2z = vb[3 * i2 + 2];

    // barycentrics — numpy op order, no FMA contraction
    const float v01x = p1x - p0x, v01y = p1y - p0y;
    const float v02x = p2x - p0x, v02y = p2y - p0y;
    const float det = (v01x * v02y) - (v01y * v02x);
    const float denom = epsclamp(det);
    const float pxr = (float)x - p0x;     // pcx - p0.x
    const float pyr = (float)y - p0y;     // pcy - p0.y
    const float l1 = ((pxr * v02y) - (pyr * v02x)) / denom;
    const float l2 = ((pyr * v01x) - (pxr * v01y)) / denom;
    const float l0 = (1.0f - l1) - l2;

    const float w0 = 1.0f / epsclamp(p0z);
    const float w1 = 1.0f / epsclamp(p1z);
    const float w2 = 1.0f / epsclamp(p2z);
    const float t0w = w0 * l0;
    const float t1w = w1 * l1;
    const float t2w = w2 * l2;
    const float zsum = (t0w + t1w) + t2w;
    const float zi = 1.0f / epsclamp(zsum);
    const float b0 = t0w * zi;
    const float b1 = t1w * zi;
    const float b2 = t2w * zi;

    const float b0m = b0 * fm, b1m = b1 * fm, b2m = b2 * fm;

    // uv gathers (8B aligned -> float2)
    const float2* __restrict__ vt2 = reinterpret_cast<const float2*>(vt);
    const float2 tA = vt2[t0i];
    const float2 tB = vt2[t1i];
    const float2 tC = vt2[t2i];
    float vtx = ((tA.x * b0) + (tB.x * b1)) + (tC.x * b2);
    float vty = ((tA.y * b0) + (tB.y * b1)) + (tC.y * b2);

    // base grid + masked lerp:  base + fm*((vt*2-1) - base)
    const float bx = (((float)x * 2.0f) + 1.0f) / (float)W - 1.0f;
    const float by = (((float)y * 2.0f) + 1.0f) / (float)H - 1.0f;
    vtx = bx + (fm * (((vtx * 2.0f) - 1.0f) - bx));
    vty = by + (fm * (((vty * 2.0f) - 1.0f) - by));

    // normal gathers
    const float* __restrict__ nb = vn + (size_t)b * V * 3;
    const float n0x = nb[3 * i0 + 0], n0y = nb[3 * i0 + 1], n0z = nb[3 * i0 + 2];
    const float n1x = nb[3 * i1 + 0], n1y = nb[3 * i1 + 1], n1z = nb[3 * i1 + 2];
    const float n2x = nb[3 * i2 + 0], n2y = nb[3 * i2 + 1], n2z = nb[3 * i2 + 2];
    const float vnx = (((n0x * b0m) + (n1x * b1m)) + (n2x * b2m)) * fm;
    const float vny = (((n0y * b0m) + (n1y * b1m)) + (n2y * b2m)) * fm;
    const float vnz = (((n0z * b0m) + (n1z * b1m)) + (n2z * b2m)) * fm;

    // ---- stores ----
    float* __restrict__ out_depth = out;                       // [NPIX]
    float* __restrict__ out_bary  = out + (size_t)NPIX;        // [NPIX,3]
    float* __restrict__ out_vt    = out + (size_t)NPIX * 4;    // [NPIX,2]
    float* __restrict__ out_vn    = out + (size_t)NPIX * 6;    // [NPIX,3]

    out_depth[p] = zi * fm;

    out_bary[3 * (size_t)p + 0] = b0m;
    out_bary[3 * (size_t)p + 1] = b1m;
    out_bary[3 * (size_t)p + 2] = b2m;

    reinterpret_cast<float2*>(out_vt)[p] = make_float2(vtx, vty);

    out_vn[3 * (size_t)p + 0] = vnx;
    out_vn[3 * (size_t)p + 1] = vny;
    out_vn[3 * (size_t)p + 2] = vnz;
}

extern "C" void kernel_launch(void* const* d_in, const int* in_sizes, int n_in,
                              void* d_out, int out_size, void* d_ws, size_t ws_size,
                              hipStream_t stream) {
    const float* v2d       = (const float*)d_in[0];
    const float* vt        = (const float*)d_in[1];
    const int*   vi        = (const int*)d_in[2];
    const int*   vti       = (const int*)d_in[3];
    const int*   index_img = (const int*)d_in[4];
    const float* vn        = (const float*)d_in[5];
    float* out = (float*)d_out;

    constexpr int NPIX = 4 * 1024 * 1024;
    dim3 grid(NPIX / 256), block(256);
    render_px<<<grid, block, 0, stream>>>(v2d, vt, vi, vti, index_img, vn, out);
}

// Round 3
// 232.752 us; speedup vs baseline: 1.2295x; 1.2295x over previous
//
#include <hip/hip_runtime.h>

// PythonRenderer — 3-pass split for per-XCD L2 locality.
//   P1: index+vi+v2d   -> depth, bary   (gather set 3.4MB/XCD w/ batch affinity)
//   P2: index+vti+vt+bary -> vt_img     (gather set 3.25MB, batch-independent)
//   P3: index+vi+vn+bary  -> vn_img     (gather set 3.4MB/XCD w/ batch affinity)
// Numerics: must stay bit-exact vs numpy (epsclamp(1e-8) amplifies last-ulp
// differences ~1e16x on degenerate tris). No FMA contraction, exact op order.
// Masked bary (b*fm) stored in P1 is reused in P2/P3 — provably identical
// final outputs (fm=1: b*fm==b bitwise; fm=0: uv collapses to base, vn to 0).

#define EPSV 1e-8f

__device__ __forceinline__ float epsclamp(float x) {
    return x < 0.0f ? fminf(x, -EPSV) : fmaxf(x, EPSV);
}

constexpr int Wd = 1024, Hd = 1024, Vd = 98304;
constexpr int NPIX = 4 * 1024 * 1024;   // B*H*W
constexpr int PIX_PER_BATCH = 1024 * 1024;

// Map blockIdx -> (batch, 256-pixel chunk) with XCD-batch affinity.
// Assumes round-robin block->XCD (xcd = blockIdx % 8): batch = xcd>>1, so
// each batch's gathers live on 2 XCDs. Bijective over 16384 blocks.
__device__ __forceinline__ int swizzled_pixel(int j, int tid) {
    const int xcd = j & 7;
    const int b = xcd >> 1;
    const int sub = ((j >> 3) << 1) + (j & 1);   // [0,4096)
    return b * PIX_PER_BATCH + sub * 256 + tid;
}

// ---------------- Pass 1: depth + bary ----------------
__global__ __launch_bounds__(256) void pass1_bary(
    const float* __restrict__ v2d,
    const int*   __restrict__ vi,
    const int*   __restrict__ index_img,
    float* __restrict__ out)
{
#pragma clang fp contract(off)
    const int p = swizzled_pixel(blockIdx.x, threadIdx.x);

    const int x = p & (Wd - 1);
    const int y = (p >> 10) & (Hd - 1);
    const int b = p >> 20;

    const int idx = index_img[p];
    const float fm = (idx != -1) ? 1.0f : 0.0f;
    const int f = (idx < 0) ? 0 : idx;

    const int i0 = vi[3 * f + 0];
    const int i1 = vi[3 * f + 1];
    const int i2 = vi[3 * f + 2];

    const float* __restrict__ vb = v2d + (size_t)b * Vd * 3;
    const float p0x = vb[3 * i0 + 0], p0y = vb[3 * i0 + 1], p0z = vb[3 * i0 + 2];
    const float p1x = vb[3 * i1 + 0], p1y = vb[3 * i1 + 1], p1z = vb[3 * i1 + 2];
    const float p2x = vb[3 * i2 + 0], p2y = vb[3 * i2 + 1], p2z = vb[3 * i2 + 2];

    const float v01x = p1x - p0x, v01y = p1y - p0y;
    const float v02x = p2x - p0x, v02y = p2y - p0y;
    const float det = (v01x * v02y) - (v01y * v02x);
    const float denom = epsclamp(det);
    const float pxr = (float)x - p0x;
    const float pyr = (float)y - p0y;
    const float l1 = ((pxr * v02y) - (pyr * v02x)) / denom;
    const float l2 = ((pyr * v01x) - (pxr * v01y)) / denom;
    const float l0 = (1.0f - l1) - l2;

    const float w0 = 1.0f / epsclamp(p0z);
    const float w1 = 1.0f / epsclamp(p1z);
    const float w2 = 1.0f / epsclamp(p2z);
    const float t0w = w0 * l0;
    const float t1w = w1 * l1;
    const float t2w = w2 * l2;
    const float zsum = (t0w + t1w) + t2w;
    const float zi = 1.0f / epsclamp(zsum);

    const float b0m = (t0w * zi) * fm;
    const float b1m = (t1w * zi) * fm;
    const float b2m = (t2w * zi) * fm;

    out[p] = zi * fm;                              // depth
    float* __restrict__ out_bary = out + (size_t)NPIX;
    out_bary[3 * (size_t)p + 0] = b0m;
    out_bary[3 * (size_t)p + 1] = b1m;
    out_bary[3 * (size_t)p + 2] = b2m;
}

// ---------------- Pass 2: uv ----------------
__global__ __launch_bounds__(256) void pass2_uv(
    const float* __restrict__ vt,
    const int*   __restrict__ vti,
    const int*   __restrict__ index_img,
    float* __restrict__ out)
{
#pragma clang fp contract(off)
    const int p = blockIdx.x * 256 + threadIdx.x;

    const int x = p & (Wd - 1);
    const int y = (p >> 10) & (Hd - 1);

    const int idx = index_img[p];
    const float fm = (idx != -1) ? 1.0f : 0.0f;
    const int f = (idx < 0) ? 0 : idx;

    const int t0i = vti[3 * f + 0];
    const int t1i = vti[3 * f + 1];
    const int t2i = vti[3 * f + 2];

    const float* __restrict__ bary = out + (size_t)NPIX;
    const float b0 = bary[3 * (size_t)p + 0];   // masked; identical result (see header)
    const float b1 = bary[3 * (size_t)p + 1];
    const float b2 = bary[3 * (size_t)p + 2];

    const float2* __restrict__ vt2 = reinterpret_cast<const float2*>(vt);
    const float2 tA = vt2[t0i];
    const float2 tB = vt2[t1i];
    const float2 tC = vt2[t2i];
    float vtx = ((tA.x * b0) + (tB.x * b1)) + (tC.x * b2);
    float vty = ((tA.y * b0) + (tB.y * b1)) + (tC.y * b2);

    const float bx = (((float)x * 2.0f) + 1.0f) / (float)Wd - 1.0f;
    const float by = (((float)y * 2.0f) + 1.0f) / (float)Hd - 1.0f;
    vtx = bx + (fm * (((vtx * 2.0f) - 1.0f) - bx));
    vty = by + (fm * (((vty * 2.0f) - 1.0f) - by));

    float* __restrict__ out_vt = out + (size_t)NPIX * 4;
    reinterpret_cast<float2*>(out_vt)[p] = make_float2(vtx, vty);
}

// ---------------- Pass 3: normals ----------------
__global__ __launch_bounds__(256) void pass3_vn(
    const float* __restrict__ vn,
    const int*   __restrict__ vi,
    const int*   __restrict__ index_img,
    float* __restrict__ out)
{
#pragma clang fp contract(off)
    const int p = swizzled_pixel(blockIdx.x, threadIdx.x);
    const int b = p >> 20;

    const int idx = index_img[p];
    const float fm = (idx != -1) ? 1.0f : 0.0f;
    const int f = (idx < 0) ? 0 : idx;

    const int i0 = vi[3 * f + 0];
    const int i1 = vi[3 * f + 1];
    const int i2 = vi[3 * f + 2];

    const float* __restrict__ bary = out + (size_t)NPIX;
    const float b0m = bary[3 * (size_t)p + 0];
    const float b1m = bary[3 * (size_t)p + 1];
    const float b2m = bary[3 * (size_t)p + 2];

    const float* __restrict__ nb = vn + (size_t)b * Vd * 3;
    const float n0x = nb[3 * i0 + 0], n0y = nb[3 * i0 + 1], n0z = nb[3 * i0 + 2];
    const float n1x = nb[3 * i1 + 0], n1y = nb[3 * i1 + 1], n1z = nb[3 * i1 + 2];
    const float n2x = nb[3 * i2 + 0], n2y = nb[3 * i2 + 1], n2z = nb[3 * i2 + 2];

    const float vnx = (((n0x * b0m) + (n1x * b1m)) + (n2x * b2m)) * fm;
    const float vny = (((n0y * b0m) + (n1y * b1m)) + (n2y * b2m)) * fm;
    const float vnz = (((n0z * b0m) + (n1z * b1m)) + (n2z * b2m)) * fm;

    float* __restrict__ out_vn = out + (size_t)NPIX * 6;
    out_vn[3 * (size_t)p + 0] = vnx;
    out_vn[3 * (size_t)p + 1] = vny;
    out_vn[3 * (size_t)p + 2] = vnz;
}

extern "C" void kernel_launch(void* const* d_in, const int* in_sizes, int n_in,
                              void* d_out, int out_size, void* d_ws, size_t ws_size,
                              hipStream_t stream) {
    const float* v2d       = (const float*)d_in[0];
    const float* vt        = (const float*)d_in[1];
    const int*   vi        = (const int*)d_in[2];
    const int*   vti       = (const int*)d_in[3];
    const int*   index_img = (const int*)d_in[4];
    const float* vn        = (const float*)d_in[5];
    float* out = (float*)d_out;

    dim3 grid(NPIX / 256), block(256);
    pass1_bary<<<grid, block, 0, stream>>>(v2d, vi, index_img, out);
    pass2_uv  <<<grid, block, 0, stream>>>(vt, vti, index_img, out);
    pass3_vn  <<<grid, block, 0, stream>>>(vn, vi, index_img, out);
}

// Round 4
// 219.164 us; speedup vs baseline: 1.3057x; 1.0620x over previous
//
#include <hip/hip_runtime.h>

// PythonRenderer — 2-pass, TA-throughput-optimized.
// Model (validated R2): divergent gathers cost ~1 cache-line access/cycle/CU;
// pass time ≈ (line-accesses/pixel) × 4M / 256CU / 2.4GHz. So: minimize the
// NUMBER of gather instructions, not bytes.
//   Pass A (batch-affine XCD swizzle): idx + vi(12B) + 3×v2d(12B) + 3×vn(12B)
//           -> depth, bary, vn. Gather set ≈ 4.6 MB/XCD.
//   Pass B: idx + vti(12B) + 3×vt(8B) + bary(coalesced) -> uv.
// Numerics: bit-exact vs numpy required (epsclamp(1e-8) amplifies last-ulp by
// ~1e16 on degenerate tris): fp contract off, exact left-to-right op order.
// Masked bary reuse in Pass B is exact (fm=1: b*fm==b bitwise; fm=0: uv
// collapses to base independent of bary).

#define EPSV 1e-8f

__device__ __forceinline__ float epsclamp(float x) {
    return x < 0.0f ? fminf(x, -EPSV) : fmaxf(x, EPSV);
}

constexpr int Wd = 1024, Hd = 1024, Vd = 98304;
constexpr int NPIX = 4 * 1024 * 1024;   // B*H*W
constexpr int PIX_PER_BATCH = 1024 * 1024;

struct I3 { int a, b, c; };           // 12B, align 4 -> dwordx3
struct F3 { float x, y, z; };         // 12B, align 4 -> dwordx3

// blockIdx -> (batch, chunk) with XCD-batch affinity (xcd = blockIdx % 8,
// batch = xcd>>1). Bijective over 16384 blocks. Perf-only assumption.
__device__ __forceinline__ int swizzled_pixel(int j, int tid) {
    const int xcd = j & 7;
    const int b = xcd >> 1;
    const int sub = ((j >> 3) << 1) + (j & 1);   // [0,4096)
    return b * PIX_PER_BATCH + sub * 256 + tid;
}

// ---------------- Pass A: depth + bary + normals ----------------
__global__ __launch_bounds__(256) void passA(
    const float* __restrict__ v2d,
    const int*   __restrict__ vi,
    const int*   __restrict__ index_img,
    const float* __restrict__ vn,
    float* __restrict__ out)
{
#pragma clang fp contract(off)
    const int p = swizzled_pixel(blockIdx.x, threadIdx.x);

    const int x = p & (Wd - 1);
    const int y = (p >> 10) & (Hd - 1);
    const int b = p >> 20;

    const int idx = index_img[p];
    const float fm = (idx != -1) ? 1.0f : 0.0f;
    const int f = (idx < 0) ? 0 : idx;

    const I3 ii = *reinterpret_cast<const I3*>(vi + 3 * (size_t)f);

    const float* __restrict__ vb = v2d + (size_t)b * Vd * 3;
    const F3 P0 = *reinterpret_cast<const F3*>(vb + 3 * (size_t)ii.a);
    const F3 P1 = *reinterpret_cast<const F3*>(vb + 3 * (size_t)ii.b);
    const F3 P2 = *reinterpret_cast<const F3*>(vb + 3 * (size_t)ii.c);

    const float* __restrict__ nb = vn + (size_t)b * Vd * 3;
    const F3 N0 = *reinterpret_cast<const F3*>(nb + 3 * (size_t)ii.a);
    const F3 N1 = *reinterpret_cast<const F3*>(nb + 3 * (size_t)ii.b);
    const F3 N2 = *reinterpret_cast<const F3*>(nb + 3 * (size_t)ii.c);

    // barycentrics — numpy op order, no FMA contraction
    const float v01x = P1.x - P0.x, v01y = P1.y - P0.y;
    const float v02x = P2.x - P0.x, v02y = P2.y - P0.y;
    const float det = (v01x * v02y) - (v01y * v02x);
    const float denom = epsclamp(det);
    const float pxr = (float)x - P0.x;
    const float pyr = (float)y - P0.y;
    const float l1 = ((pxr * v02y) - (pyr * v02x)) / denom;
    const float l2 = ((pyr * v01x) - (pxr * v01y)) / denom;
    const float l0 = (1.0f - l1) - l2;

    const float w0 = 1.0f / epsclamp(P0.z);
    const float w1 = 1.0f / epsclamp(P1.z);
    const float w2 = 1.0f / epsclamp(P2.z);
    const float t0w = w0 * l0;
    const float t1w = w1 * l1;
    const float t2w = w2 * l2;
    const float zsum = (t0w + t1w) + t2w;
    const float zi = 1.0f / epsclamp(zsum);

    const float b0m = (t0w * zi) * fm;
    const float b1m = (t1w * zi) * fm;
    const float b2m = (t2w * zi) * fm;

    const float vnx = (((N0.x * b0m) + (N1.x * b1m)) + (N2.x * b2m)) * fm;
    const float vny = (((N0.y * b0m) + (N1.y * b1m)) + (N2.y * b2m)) * fm;
    const float vnz = (((N0.z * b0m) + (N1.z * b1m)) + (N2.z * b2m)) * fm;

    out[p] = zi * fm;                              // depth
    float* __restrict__ out_bary = out + (size_t)NPIX;
    out_bary[3 * (size_t)p + 0] = b0m;
    out_bary[3 * (size_t)p + 1] = b1m;
    out_bary[3 * (size_t)p + 2] = b2m;
    float* __restrict__ out_vn = out + (size_t)NPIX * 6;
    out_vn[3 * (size_t)p + 0] = vnx;
    out_vn[3 * (size_t)p + 1] = vny;
    out_vn[3 * (size_t)p + 2] = vnz;
}

// ---------------- Pass B: uv ----------------
__global__ __launch_bounds__(256) void passB(
    const float* __restrict__ vt,
    const int*   __restrict__ vti,
    const int*   __restrict__ index_img,
    float* __restrict__ out)
{
#pragma clang fp contract(off)
    const int p = blockIdx.x * 256 + threadIdx.x;

    const int x = p & (Wd - 1);
    const int y = (p >> 10) & (Hd - 1);

    const int idx = index_img[p];
    const float fm = (idx != -1) ? 1.0f : 0.0f;
    const int f = (idx < 0) ? 0 : idx;

    const I3 tt = *reinterpret_cast<const I3*>(vti + 3 * (size_t)f);

    const float* __restrict__ bary = out + (size_t)NPIX;
    const float b0 = bary[3 * (size_t)p + 0];   // masked; result identical (header)
    const float b1 = bary[3 * (size_t)p + 1];
    const float b2 = bary[3 * (size_t)p + 2];

    const float2* __restrict__ vt2 = reinterpret_cast<const float2*>(vt);
    const float2 tA = vt2[tt.a];
    const float2 tB = vt2[tt.b];
    const float2 tC = vt2[tt.c];
    float vtx = ((tA.x * b0) + (tB.x * b1)) + (tC.x * b2);
    float vty = ((tA.y * b0) + (tB.y * b1)) + (tC.y * b2);

    const float bx = (((float)x * 2.0f) + 1.0f) / (float)Wd - 1.0f;
    const float by = (((float)y * 2.0f) + 1.0f) / (float)Hd - 1.0f;
    vtx = bx + (fm * (((vtx * 2.0f) - 1.0f) - bx));
    vty = by + (fm * (((vty * 2.0f) - 1.0f) - by));

    float* __restrict__ out_vt = out + (size_t)NPIX * 4;
    reinterpret_cast<float2*>(out_vt)[p] = make_float2(vtx, vty);
}

extern "C" void kernel_launch(void* const* d_in, const int* in_sizes, int n_in,
                              void* d_out, int out_size, void* d_ws, size_t ws_size,
                              hipStream_t stream) {
    const float* v2d       = (const float*)d_in[0];
    const float* vt        = (const float*)d_in[1];
    const int*   vi        = (const int*)d_in[2];
    const int*   vti       = (const int*)d_in[3];
    const int*   index_img = (const int*)d_in[4];
    const float* vn        = (const float*)d_in[5];
    float* out = (float*)d_out;

    dim3 grid(NPIX / 256), block(256);
    passA<<<grid, block, 0, stream>>>(v2d, vi, index_img, vn, out);
    passB<<<grid, block, 0, stream>>>(vt, vti, index_img, out);
}